// Round 18
// baseline (268.603 us; speedup 1.0000x reference)
//
#include <hip/hip_runtime.h>
#include <math.h>

#define NN 50000
#define NE 800000
#define TDIM 100
#define MAXCH 100000   // sum ceil(deg/16) <= 50000 + 800000/16 = 100000
#define NBLK 196       // ceil(NN/256)
#define EGRID 2048     // persistent k_edge blocks
#define PBLK 1563      // ceil(NN/32)  proj blocks
#define FBLK 1563      // ceil(NE/512) elist-fill blocks
#define CBLK 98        // ceil(NN/512) chunk-table blocks

typedef _Float16 half2v __attribute__((ext_vector_type(2)));
typedef _Float16 half4v __attribute__((ext_vector_type(4)));
typedef _Float16 half8v __attribute__((ext_vector_type(8)));
typedef __fp16 fp16x2 __attribute__((ext_vector_type(2)));
typedef float f32x4 __attribute__((ext_vector_type(4)));

union U16 { uint4 u; half8v h; };
union U4h { unsigned u; half2v h; };

// cos(x) matching np.cos(float32) to ~1e-6.
__device__ __forceinline__ float ref_cosf(float x) {
  const float C1 = 0.15915494f;
  const float C2 = 6.42063831e-9f;
  float p = x * C1;
  float r = __fmaf_rn(x, C1, -p);
  r = __fmaf_rn(x, C2, r);
  float n = rintf(p);
  float f = (p - n) + r;
  return __builtin_amdgcn_cosf(f);
}

__device__ __forceinline__ unsigned pk16(float a, float b) {
  fp16x2 h = __builtin_amdgcn_cvt_pkrtz(a, b);
  unsigned u;
  __builtin_memcpy(&u, &h, 4);
  return u;
}

__device__ __forceinline__ float fdot2f(unsigned a, unsigned b, float c) {
  U4h ua, ub; ua.u = a; ub.u = b;
#if __has_builtin(__builtin_amdgcn_fdot2)
  return __builtin_amdgcn_fdot2(ua.h, ub.h, c, false);
#else
  return c + (float)ua.h.x * (float)ub.h.x + (float)ua.h.y * (float)ub.h.y;
#endif
}

// packed f16 helpers (v_pk_add_f16 / v_pk_mul_f16)
__device__ __forceinline__ unsigned pkadd(unsigned a, unsigned b) {
  half2v x, y; __builtin_memcpy(&x, &a, 4); __builtin_memcpy(&y, &b, 4);
  half2v z = x + y; unsigned r; __builtin_memcpy(&r, &z, 4); return r;
}
__device__ __forceinline__ unsigned pkmul(unsigned a, unsigned b) {
  half2v x, y; __builtin_memcpy(&x, &a, 4); __builtin_memcpy(&y, &b, 4);
  half2v z = x * y; unsigned r; __builtin_memcpy(&r, &z, 4); return r;
}

// ---- DPP 16-lane butterfly (VALU pipe): masks {1,2,7,15} -------------------
template<int CTRL>
__device__ __forceinline__ int dpp_i(int x) {
  return __builtin_amdgcn_update_dpp(0, x, CTRL, 0xf, 0xf, true);
}
template<int CTRL>
__device__ __forceinline__ float dpp_addf(float x) {
  return x + __int_as_float(dpp_i<CTRL>(__float_as_int(x)));
}
template<int CTRL>
__device__ __forceinline__ float dpp_maxf(float x) {
  return fmaxf(x, __int_as_float(dpp_i<CTRL>(__float_as_int(x))));
}
__device__ __forceinline__ float red16_add(float x) {
  x = dpp_addf<0xB1>(x); x = dpp_addf<0x4E>(x);
  x = dpp_addf<0x141>(x); x = dpp_addf<0x140>(x);
  return x;
}
__device__ __forceinline__ float red16_max(float x) {
  x = dpp_maxf<0xB1>(x); x = dpp_maxf<0x4E>(x);
  x = dpp_maxf<0x141>(x); x = dpp_maxf<0x140>(x);
  return x;
}
__device__ __forceinline__ unsigned red16_pkadd(unsigned x) {
  x = pkadd(x, (unsigned)dpp_i<0xB1>((int)x));
  x = pkadd(x, (unsigned)dpp_i<0x4E>((int)x));
  x = pkadd(x, (unsigned)dpp_i<0x141>((int)x));
  x = pkadd(x, (unsigned)dpp_i<0x140>((int)x));
  return x;
}

// attr fragments: lane slice g, j = ks*32 + g*8 + 2p (+1); j>100 -> 0
__device__ __forceinline__ void build_bfu(float rel_b, float mg_b, int g,
                                          const float2* wtbt_s, unsigned bfu[4][4]) {
#pragma unroll
  for (int ks = 0; ks < 4; ++ks) {
#pragma unroll
    for (int p = 0; p < 4; ++p) {
      int j0 = ks * 32 + g * 8 + 2 * p;
      float a0 = 0.f, a1 = 0.f;
      if (ks < 3) {
        float2 w0 = wtbt_s[j0], w1 = wtbt_s[j0 + 1];
        a0 = ref_cosf(__fmaf_rn(rel_b, w0.x, w0.y));
        a1 = ref_cosf(__fmaf_rn(rel_b, w1.x, w1.y));
      } else {
        if (j0 < 100) {
          float2 w0 = wtbt_s[j0];
          a0 = ref_cosf(__fmaf_rn(rel_b, w0.x, w0.y));
        } else if (j0 == 100) a0 = mg_b;
        if (j0 + 1 < 100) {
          float2 w1 = wtbt_s[j0 + 1];
          a1 = ref_cosf(__fmaf_rn(rel_b, w1.x, w1.y));
        } else if (j0 + 1 == 100) a1 = mg_b;
      }
      bfu[ks][p] = pk16(a0, a1);
    }
  }
}

// ---------------- k_init: W fragments + degree count (fused) ---------------
__global__ void k_init(const float* __restrict__ We,
                       const float* __restrict__ Wq, const float* __restrict__ Wk,
                       const float* __restrict__ Wv, const float* __restrict__ Wskip,
                       uint4* __restrict__ wef, uint4* __restrict__ wpf,
                       const int* __restrict__ ei, int* __restrict__ deg) {
  int idx = blockIdx.x * 256 + threadIdx.x;
  if (idx < 2048) {
    int lane = idx & 63, fi = idx >> 6;
    int ks = fi >> 3, mt = fi & 7;
    int ch = mt * 16 + (lane & 15);
    int k0 = ks * 32 + ((lane >> 4) << 3);
    U16 cv;
#pragma unroll
    for (int jj = 0; jj < 8; ++jj) {
      int j = k0 + jj;
      cv.h[jj] = (j <= 100) ? (_Float16)We[j * 128 + ch] : (_Float16)0.f;
    }
    wef[idx] = cv.u;
  } else if (idx < 2048 + 8192) {
    int i2 = idx - 2048;
    int lane = i2 & 63, fi = i2 >> 6;     // fi = (cy*4+ks)*8+nt
    int nt = fi & 7, ks = (fi >> 3) & 3, cy = fi >> 5;
    const float* W = (cy == 0) ? Wq : (cy == 1) ? Wk : (cy == 2) ? Wv : Wskip;
    int n = nt * 16 + (lane & 15);
    int k0 = ks * 32 + ((lane >> 4) << 3);
    U16 cv;
#pragma unroll
    for (int jj = 0; jj < 8; ++jj)
      cv.h[jj] = (_Float16)W[(k0 + jj) * 128 + n];
    wpf[i2] = cv.u;
  }
  if (idx < NE) atomicAdd(&deg[ei[NE + idx]], 1);
}

// ---------------- parallel CSR scan (2 kernels) ----------------------------
__global__ __launch_bounds__(256) void k_scan1(const int* __restrict__ deg,
                                               int* __restrict__ off,
                                               int* __restrict__ choff,
                                               int* __restrict__ bsum,
                                               int* __restrict__ bsumc) {
  __shared__ int s[256], sc[256];
  const int b = blockIdx.x, t = threadIdx.x;
  const int n = b * 256 + t;
  int d = (n < NN) ? deg[n] : 0;
  int c = (d + 15) >> 4;
  s[t] = d; sc[t] = c;
  __syncthreads();
  for (int o = 1; o < 256; o <<= 1) {
    int v1 = 0, v2 = 0;
    if (t >= o) { v1 = s[t - o]; v2 = sc[t - o]; }
    __syncthreads();
    if (t >= o) { s[t] += v1; sc[t] += v2; }
    __syncthreads();
  }
  if (n < NN) { off[n] = s[t] - d; choff[n] = sc[t] - c; }
  if (t == 255) { bsum[b] = s[255]; bsumc[b] = sc[255]; }
}

// merged scan2+scan3: every block redundantly scans the 196 block sums,
// then adds its exclusive base to its 256 nodes.
__global__ __launch_bounds__(256) void k_scanf(const int* __restrict__ bsum,
                                               const int* __restrict__ bsumc,
                                               int* __restrict__ off,
                                               int* __restrict__ choff) {
  __shared__ int s[256], sc[256];
  const int b = blockIdx.x, t = threadIdx.x;
  s[t] = (t < NBLK) ? bsum[t] : 0;
  sc[t] = (t < NBLK) ? bsumc[t] : 0;
  __syncthreads();
  for (int o = 1; o < 256; o <<= 1) {
    int v1 = 0, v2 = 0;
    if (t >= o) { v1 = s[t - o]; v2 = sc[t - o]; }
    __syncthreads();
    if (t >= o) { s[t] += v1; sc[t] += v2; }
    __syncthreads();
  }
  int base = (b > 0) ? s[b - 1] : 0;
  int basec = (b > 0) ? sc[b - 1] : 0;
  int n = b * 256 + t;
  if (n < NN) { off[n] += base; choff[n] += basec; }
  if (b == 0 && t == 0) { off[NN] = s[NBLK - 1]; choff[NN] = sc[NBLK - 1]; }
}

// ---------------- k_mid: proj (MFMA) + elist fill + chunk table, one launch -
// blocks [0,PBLK): projection of 32 rows; [PBLK,PBLK+FBLK): elist fill;
// [PBLK+FBLK, +CBLK): chunk table. Branch is block-uniform. The atomic
// scatter overlaps the MFMA blocks' execution (complementary pipes).
// Q,K,V stored PERMUTED: channel c -> ((c>>2)&3)*32 + (c>>4)*4 + (c&3).
__global__ __launch_bounds__(512) void k_mid(
    const float* __restrict__ x,
    const float* __restrict__ bq, const float* __restrict__ bk,
    const float* __restrict__ bv, const float* __restrict__ bskip,
    const uint4* __restrict__ wpf,
    _Float16* __restrict__ Q16, _Float16* __restrict__ K16,
    _Float16* __restrict__ V16, _Float16* __restrict__ S16,
    const int* __restrict__ ei, const int* __restrict__ deg,
    const int* __restrict__ off, const int* __restrict__ choff,
    int* __restrict__ cur, int* __restrict__ elist,
    uint2* __restrict__ chunks)
{
  __shared__ unsigned xs[32][68];     // x rows as f16 pairs (272B pitch)
  __shared__ _Float16 os[32][136];    // output bounce (272B pitch)

  const int tid = threadIdx.x;
  const int b = blockIdx.x;

  if (b >= PBLK) {
    if (b < PBLK + FBLK) {
      int e = (b - PBLK) * 512 + tid;
      if (e < NE) {
        int d = ei[NE + e];
        int p = atomicAdd(&cur[d], 1);
        elist[off[d] + p] = e;
      }
    } else {
      int n = (b - PBLK - FBLK) * 512 + tid;
      if (n < NN) {
        int d = deg[n], o = off[n], c = choff[n];
        int nch = (d + 15) >> 4;
        unsigned flag = (nch == 1) ? 0x80000000u : 0u;
        for (int j = 0; j < nch; ++j) {
          int cnt = d - 16 * j; if (cnt > 16) cnt = 16;
          chunks[c + j] = make_uint2((unsigned)(o + 16 * j),
                                     flag | ((unsigned)n << 5) | (unsigned)cnt);
        }
      }
    }
    return;
  }

  const int n0 = b * 32;
  {
    int r = tid >> 4, c8 = (tid & 15) * 8;     // 32 rows x 16 col-groups of 8
    int row = n0 + r;
    float4 v0 = {0,0,0,0}, v1 = {0,0,0,0};
    if (row < NN) {
      const float4* xp = (const float4*)&x[(size_t)row * 128 + c8];
      v0 = xp[0]; v1 = xp[1];
    }
    unsigned* xr = &xs[r][c8 >> 1];
    xr[0] = pk16(v0.x, v0.y); xr[1] = pk16(v0.z, v0.w);
    xr[2] = pk16(v1.x, v1.y); xr[3] = pk16(v1.z, v1.w);
  }
  __syncthreads();

  const int w = tid >> 6, lane = tid & 63;
  const int cy = w >> 1, half = w & 1;

  f32x4 acc[2][4] = {};
#pragma unroll
  for (int ks = 0; ks < 4; ++ks) {
    U16 a0_, a1_;
    a0_.u = *(const uint4*)&xs[lane & 15][ks * 16 + ((lane >> 4) << 2)];
    a1_.u = *(const uint4*)&xs[16 + (lane & 15)][ks * 16 + ((lane >> 4) << 2)];
#pragma unroll
    for (int nt = 0; nt < 4; ++nt) {
      U16 b_; b_.u = wpf[((cy * 4 + ks) * 8 + half * 4 + nt) * 64 + lane];
      acc[0][nt] = __builtin_amdgcn_mfma_f32_16x16x32_f16(a0_.h, b_.h, acc[0][nt], 0, 0, 0);
      acc[1][nt] = __builtin_amdgcn_mfma_f32_16x16x32_f16(a1_.h, b_.h, acc[1][nt], 0, 0, 0);
    }
  }

  const float* biases[4] = {bq, bk, bv, bskip};
  _Float16* dsts[4] = {Q16, K16, V16, S16};
#pragma unroll
  for (int c = 0; c < 4; ++c) {
    __syncthreads();
    if (cy == c) {
#pragma unroll
      for (int nt = 0; nt < 4; ++nt) {
        int col = half * 64 + nt * 16 + (lane & 15);
        float bb = biases[c][col];
        int rb = (lane >> 4) << 2;
#pragma unroll
        for (int mt2 = 0; mt2 < 2; ++mt2)
#pragma unroll
          for (int reg = 0; reg < 4; ++reg)
            os[mt2 * 16 + rb + reg][col] = (_Float16)(acc[mt2][nt][reg] + bb);
      }
    }
    __syncthreads();
    {
      int r = tid >> 4, c8 = (tid & 15) * 8;
      int row = n0 + r;
      if (row < NN) {
        _Float16* dst = dsts[c];
        const _Float16* op = &os[r][c8];
        if (c < 3) {
#pragma unroll
          for (int q = 0; q < 2; ++q) {
            int j4 = (c8 >> 2) + q;
            int po = ((j4 & 3) << 5) | ((j4 >> 2) << 2);
            *(half4v*)&dst[(size_t)row * 128 + po] = *(const half4v*)&op[q * 4];
          }
        } else {
          *(uint4*)&dst[(size_t)row * 128 + c8] = *((const uint4*)op);
        }
      }
    }
  }
}

// ---------------- k_edge: persistent blocks, one wave per 16-edge chunk -----
// wef staged once per block; grid-stride over chunks. Single-chunk nodes are
// finished INLINE (skip+relu+layernorm; identical math to k_comb with sc=1).
__global__ __launch_bounds__(512) void k_edge(
    const _Float16* __restrict__ Q16, const _Float16* __restrict__ K16,
    const _Float16* __restrict__ V16, const _Float16* __restrict__ S16,
    const float* __restrict__ Wt, const float* __restrict__ bt,
    const uint4* __restrict__ wefrag,
    const float* __restrict__ gamma, const float* __restrict__ beta,
    const float* __restrict__ msg, const int* __restrict__ last_update,
    const int* __restrict__ ei, const int* __restrict__ tt,
    const int* __restrict__ elist, const uint2* __restrict__ chunks,
    const int* __restrict__ choff,
    unsigned* __restrict__ numbuf, float4* __restrict__ mdm,
    float4* __restrict__ mdd, float* __restrict__ out)
{
  __shared__ uint4 wef_s[2048];
  __shared__ float2 wtbt_s[104];
  __shared__ unsigned accs_u[8][64];

  for (int i = threadIdx.x; i < 2048; i += 512) wef_s[i] = wefrag[i];
  if (threadIdx.x < 104) {
    int j = threadIdx.x;
    wtbt_s[j] = make_float2(j < TDIM ? Wt[j] : 0.f, j < TDIM ? bt[j] : 0.f);
  }
  __syncthreads();

  const int nchunks = choff[NN];
  const int wid = threadIdx.x >> 6, lane = threadIdx.x & 63;
  const int g = lane >> 4, ed = lane & 15;

  for (int c0 = blockIdx.x * 8; c0 < nchunks; c0 += EGRID * 8) {
    const int chunk = c0 + wid;
    if (chunk >= nchunks) continue;   // no block-wide sync in body: safe

    uint2 ce = chunks[chunk];
    const int estart = (int)ce.x;
    const int node = (int)((ce.y >> 5) & 0xFFFFu);
    const int cnt = (int)(ce.y & 31u);

    const int edc = (ed < cnt) ? ed : (cnt - 1);
    const int eid = elist[estart + edc];
    const int src_b = ei[eid];
    const float mg_b = msg[eid];
    const float rel_b = (float)(last_update[src_b] - tt[eid]);
    const bool valid = (ed < cnt);

    unsigned bfu[4][4];
    build_bfu(rel_b, mg_b, g, wtbt_s, bfu);

    // e via MFMA: ec[mt][r] = e[ed][mt*16+g*4+r]
    f32x4 ec[8];
#pragma unroll
    for (int mt = 0; mt < 8; ++mt) {
      f32x4 c4 = {0.f, 0.f, 0.f, 0.f};
#pragma unroll
      for (int ks = 0; ks < 4; ++ks) {
        U16 av2; av2.u = wef_s[(ks * 8 + mt) * 64 + lane];
        U16 bv2; bv2.u.x = bfu[ks][0]; bv2.u.y = bfu[ks][1];
        bv2.u.z = bfu[ks][2]; bv2.u.w = bfu[ks][3];
        c4 = __builtin_amdgcn_mfma_f32_16x16x32_f16(av2.h, bv2.h, c4, 0, 0, 0);
      }
      ec[mt] = c4;
    }

    // pack e to f16 pairs; pair layout matches permuted q/k/v uint4 blocks
    unsigned ep2[16];
#pragma unroll
    for (int mt = 0; mt < 8; ++mt) {
      ep2[mt * 2 + 0] = pk16(ec[mt][0], ec[mt][1]);
      ep2[mt * 2 + 1] = pk16(ec[mt][2], ec[mt][3]);
    }

    // per-head alpha = q.k + q.e via fdot2
    float pal[4];
    {
      const uint4* qp = (const uint4*)&Q16[(size_t)node * 128 + g * 32];
      const uint4* kp = (const uint4*)&K16[(size_t)src_b * 128 + g * 32];
#pragma unroll
      for (int i = 0; i < 4; ++i) {
        uint4 qa = qp[i], ka = kp[i];
        float p = 0.f;
        p = fdot2f(qa.x, ka.x, p); p = fdot2f(qa.y, ka.y, p);
        p = fdot2f(qa.z, ka.z, p); p = fdot2f(qa.w, ka.w, p);
        p = fdot2f(qa.x, ep2[4 * i + 0], p); p = fdot2f(qa.y, ep2[4 * i + 1], p);
        p = fdot2f(qa.z, ep2[4 * i + 2], p); p = fdot2f(qa.w, ep2[4 * i + 3], p);
        pal[i] = p;
      }
    }

    // per-head: complete dot across g-lanes (shfl), chunk softmax via DPP
    float m_[4], w_[4], d_[4];
#pragma unroll
    for (int h = 0; h < 4; ++h) {
      float p = pal[h];
      p += __shfl_xor(p, 16); p += __shfl_xor(p, 32);
      float al = valid ? p * 0.17677669529663689f : -INFINITY;
      float mm = red16_max(al);
      m_[h] = mm;
      w_[h] = __expf(al - mm);       // invalid -> 0
      d_[h] = red16_add(w_[h]);
    }

    // partial num in packed f16: w*(v+e), reduced over ed with packed DPP
    unsigned np2[16];
    {
      const uint4* vp = (const uint4*)&V16[(size_t)src_b * 128 + g * 32];
#pragma unroll
      for (int i = 0; i < 4; ++i) {
        uint4 va = vp[i];
        unsigned w2 = pk16(w_[i], w_[i]);
        np2[4 * i + 0] = pkmul(pkadd(va.x, ep2[4 * i + 0]), w2);
        np2[4 * i + 1] = pkmul(pkadd(va.y, ep2[4 * i + 1]), w2);
        np2[4 * i + 2] = pkmul(pkadd(va.z, ep2[4 * i + 2]), w2);
        np2[4 * i + 3] = pkmul(pkadd(va.w, ep2[4 * i + 3]), w2);
      }
    }
#pragma unroll
    for (int j = 0; j < 16; ++j) np2[j] = red16_pkadd(np2[j]);

    // stash reduced pairs: natural pair index P = 16i + 8(j>>1) + 2g + (j&1)
    if (ed == 0) {
#pragma unroll
      for (int i = 0; i < 4; ++i)
#pragma unroll
        for (int j = 0; j < 4; ++j)
          accs_u[wid][16 * i + 8 * (j >> 1) + 2 * g + (j & 1)] = np2[4 * i + j];
    }
    __asm__ volatile("s_waitcnt lgkmcnt(0)" ::: "memory");

    unsigned pr = accs_u[wid][lane];
    if (!(ce.y & 0x80000000u)) {
      numbuf[(size_t)chunk * 64 + lane] = pr;
      if (lane == 0) {
        mdm[chunk] = make_float4(m_[0], m_[1], m_[2], m_[3]);
        mdd[chunk] = make_float4(d_[0], d_[1], d_[2], d_[3]);
      }
    } else {
      // single-chunk node: finish inline (sc = exp(m-M) = 1)
      float dg = (g & 2) ? ((g & 1) ? d_[3] : d_[2])
                         : ((g & 1) ? d_[1] : d_[0]);
      float iv = 1.f / (dg + 1e-16f);
      U4h u; u.u = pr;
      U4h s2; s2.u = *(const unsigned*)&S16[(size_t)node * 128 + 2 * lane];
      float r0 = fmaxf(fmaf((float)u.h.x, iv, (float)s2.h.x), 0.f);
      float r1 = fmaxf(fmaf((float)u.h.y, iv, (float)s2.h.y), 0.f);
      float sum = r0 + r1;
#pragma unroll
      for (int o = 1; o < 64; o <<= 1) sum += __shfl_xor(sum, o);
      float mu = sum * 0.0078125f;
      float dd0 = r0 - mu, dd1 = r1 - mu;
      float vs = dd0 * dd0 + dd1 * dd1;
#pragma unroll
      for (int o = 1; o < 64; o <<= 1) vs += __shfl_xor(vs, o);
      float rstd = rsqrtf(vs * 0.0078125f + 1e-5f);
      float2 gm = ((const float2*)gamma)[lane], bb = ((const float2*)beta)[lane];
      ((float2*)out)[node * 64 + lane] =
          make_float2(dd0 * rstd * gm.x + bb.x, dd1 * rstd * gm.y + bb.y);
    }
  }
}

// ---------------- k_comb: per-head flash combine (multi-chunk nodes only) ---
__global__ __launch_bounds__(256) void k_comb(
    const unsigned* __restrict__ numbuf, const float* __restrict__ mdmf,
    const float* __restrict__ mddf, const _Float16* __restrict__ S16,
    const float* __restrict__ gamma, const float* __restrict__ beta,
    const int* __restrict__ choff, float* __restrict__ out)
{
  const int wid = threadIdx.x >> 6, lane = threadIdx.x & 63;
  const int node = blockIdx.x * 4 + wid;
  const int g = lane >> 4;          // head of channels 2*lane, 2*lane+1
  const int c0 = choff[node], c1 = choff[node + 1];
  if (c1 - c0 == 1) return;         // finished inline by k_edge

  float M = -INFINITY;
  for (int c = c0; c < c1; ++c) M = fmaxf(M, mdmf[c * 4 + g]);

  float den = 0.f, n0 = 0.f, n1 = 0.f;
  for (int c = c0; c < c1; ++c) {
    float sc = __expf(mdmf[c * 4 + g] - M);
    den = fmaf(mddf[c * 4 + g], sc, den);
    U4h u; u.u = numbuf[(size_t)c * 64 + lane];
    n0 = fmaf((float)u.h.x, sc, n0);
    n1 = fmaf((float)u.h.y, sc, n1);
  }

  float iv = 1.f / (den + 1e-16f);
  U4h s2; s2.u = *(const unsigned*)&S16[(size_t)node * 128 + 2 * lane];
  float r0 = fmaxf(fmaf(n0, iv, (float)s2.h.x), 0.f);
  float r1 = fmaxf(fmaf(n1, iv, (float)s2.h.y), 0.f);

  float sum = r0 + r1;
#pragma unroll
  for (int o = 1; o < 64; o <<= 1) sum += __shfl_xor(sum, o);
  float mu = sum * 0.0078125f;
  float d0 = r0 - mu, d1 = r1 - mu;
  float vs = d0 * d0 + d1 * d1;
#pragma unroll
  for (int o = 1; o < 64; o <<= 1) vs += __shfl_xor(vs, o);
  float rstd = rsqrtf(vs * 0.0078125f + 1e-5f);
  float2 gm = ((const float2*)gamma)[lane], bb = ((const float2*)beta)[lane];
  ((float2*)out)[node * 64 + lane] =
      make_float2(d0 * rstd * gm.x + bb.x, d1 * rstd * gm.y + bb.y);
}

// ---------------- launch ----------------
// ws (bytes): Q16 0 | S16 12.8M | K16 25.6M | V16 38.4M | numbuf 51.2M (25.6M)
//   deg 76.8M | cur 77.0M | off 77.2M | choff 77,400,064 | elist 77,600,128
//   wef 80,800,128 | chunks 80,832,896 | mdm 81,632,896 | mdd 83,232,896
//   wpf 84,832,896 (128KB) | bsum 84,963,968 | bsumc 84,964,968 | end 84,965,968
extern "C" void kernel_launch(void* const* d_in, const int* in_sizes, int n_in,
                              void* d_out, int out_size, void* d_ws, size_t ws_size,
                              hipStream_t stream)
{
  (void)in_sizes; (void)n_in; (void)out_size;
  if (ws_size < 84965968u) return;

  const float* x     = (const float*)d_in[0];
  const float* msg   = (const float*)d_in[1];
  const float* Wt    = (const float*)d_in[2];
  const float* bt    = (const float*)d_in[3];
  const float* Wq    = (const float*)d_in[4];
  const float* bq    = (const float*)d_in[5];
  const float* Wk    = (const float*)d_in[6];
  const float* bk    = (const float*)d_in[7];
  const float* Wv    = (const float*)d_in[8];
  const float* bv    = (const float*)d_in[9];
  const float* We    = (const float*)d_in[10];
  const float* Wskip = (const float*)d_in[11];
  const float* bskip = (const float*)d_in[12];
  const float* gamma = (const float*)d_in[13];
  const float* beta  = (const float*)d_in[14];
  const int* last_update = (const int*)d_in[15];
  const int* ei    = (const int*)d_in[16];
  const int* tt    = (const int*)d_in[17];

  char* ws = (char*)d_ws;
  _Float16* Q16 = (_Float16*)(ws);
  _Float16* S16 = (_Float16*)(ws + 12800000);
  _Float16* K16 = (_Float16*)(ws + 25600000);
  _Float16* V16 = (_Float16*)(ws + 38400000);
  unsigned* numbuf = (unsigned*)(ws + 51200000);
  int* deg   = (int*)(ws + 76800000);
  int* cur   = (int*)(ws + 77000000);
  int* off   = (int*)(ws + 77200000);
  int* choff = (int*)(ws + 77400064);
  int* elist = (int*)(ws + 77600128);
  uint4* wef = (uint4*)(ws + 80800128);
  uint2* chunks = (uint2*)(ws + 80832896);
  float4* mdm = (float4*)(ws + 81632896);
  float4* mdd = (float4*)(ws + 83232896);
  uint4* wpf = (uint4*)(ws + 84832896);
  int* bsum  = (int*)(ws + 84963968);
  int* bsumc = (int*)(ws + 84964968);

  (void)hipMemsetAsync(deg, 0, 400000, stream);        // deg + cur
  k_init<<<(NE + 255) / 256, 256, 0, stream>>>(We, Wq, Wk, Wv, Wskip, wef, wpf,
                                               ei, deg);
  k_scan1<<<NBLK, 256, 0, stream>>>(deg, off, choff, bsum, bsumc);
  k_scanf<<<NBLK, 256, 0, stream>>>(bsum, bsumc, off, choff);
  k_mid<<<PBLK + FBLK + CBLK, 512, 0, stream>>>(x, bq, bk, bv, bskip, wpf,
                                                Q16, K16, V16, S16,
                                                ei, deg, off, choff,
                                                cur, elist, chunks);
  k_edge<<<EGRID, 512, 0, stream>>>(Q16, K16, V16, S16, Wt, bt, wef,
                                    gamma, beta, msg, last_update, ei, tt,
                                    elist, chunks, choff, numbuf, mdm, mdd,
                                    (float*)d_out);
  k_comb<<<NN / 4, 256, 0, stream>>>(numbuf, (const float*)mdm, (const float*)mdd,
                                     S16, gamma, beta, choff, (float*)d_out);
}

// Round 19
// 265.496 us; speedup vs baseline: 1.0117x; 1.0117x over previous
//
#include <hip/hip_runtime.h>
#include <math.h>

#define NN 50000
#define NE 800000
#define TDIM 100
#define MAXCH 100000   // sum ceil(deg/16) <= 50000 + 800000/16 = 100000
#define NBLK 196       // ceil(NN/256)
#define EGRID 2048     // persistent k_edge blocks

typedef _Float16 half2v __attribute__((ext_vector_type(2)));
typedef _Float16 half4v __attribute__((ext_vector_type(4)));
typedef _Float16 half8v __attribute__((ext_vector_type(8)));
typedef __fp16 fp16x2 __attribute__((ext_vector_type(2)));
typedef float f32x4 __attribute__((ext_vector_type(4)));

union U16 { uint4 u; half8v h; };
union U4h { unsigned u; half2v h; };

// cos(x) matching np.cos(float32) to ~1e-6.
__device__ __forceinline__ float ref_cosf(float x) {
  const float C1 = 0.15915494f;
  const float C2 = 6.42063831e-9f;
  float p = x * C1;
  float r = __fmaf_rn(x, C1, -p);
  r = __fmaf_rn(x, C2, r);
  float n = rintf(p);
  float f = (p - n) + r;
  return __builtin_amdgcn_cosf(f);
}

__device__ __forceinline__ unsigned pk16(float a, float b) {
  fp16x2 h = __builtin_amdgcn_cvt_pkrtz(a, b);
  unsigned u;
  __builtin_memcpy(&u, &h, 4);
  return u;
}

__device__ __forceinline__ float fdot2f(unsigned a, unsigned b, float c) {
  U4h ua, ub; ua.u = a; ub.u = b;
#if __has_builtin(__builtin_amdgcn_fdot2)
  return __builtin_amdgcn_fdot2(ua.h, ub.h, c, false);
#else
  return c + (float)ua.h.x * (float)ub.h.x + (float)ua.h.y * (float)ub.h.y;
#endif
}

// packed f16 helpers (v_pk_add_f16 / v_pk_mul_f16)
__device__ __forceinline__ unsigned pkadd(unsigned a, unsigned b) {
  half2v x, y; __builtin_memcpy(&x, &a, 4); __builtin_memcpy(&y, &b, 4);
  half2v z = x + y; unsigned r; __builtin_memcpy(&r, &z, 4); return r;
}
__device__ __forceinline__ unsigned pkmul(unsigned a, unsigned b) {
  half2v x, y; __builtin_memcpy(&x, &a, 4); __builtin_memcpy(&y, &b, 4);
  half2v z = x * y; unsigned r; __builtin_memcpy(&r, &z, 4); return r;
}

// ---- DPP 16-lane butterfly (VALU pipe): masks {1,2,7,15} -------------------
template<int CTRL>
__device__ __forceinline__ int dpp_i(int x) {
  return __builtin_amdgcn_update_dpp(0, x, CTRL, 0xf, 0xf, true);
}
template<int CTRL>
__device__ __forceinline__ float dpp_addf(float x) {
  return x + __int_as_float(dpp_i<CTRL>(__float_as_int(x)));
}
template<int CTRL>
__device__ __forceinline__ float dpp_maxf(float x) {
  return fmaxf(x, __int_as_float(dpp_i<CTRL>(__float_as_int(x))));
}
__device__ __forceinline__ float red16_add(float x) {
  x = dpp_addf<0xB1>(x); x = dpp_addf<0x4E>(x);
  x = dpp_addf<0x141>(x); x = dpp_addf<0x140>(x);
  return x;
}
__device__ __forceinline__ float red16_max(float x) {
  x = dpp_maxf<0xB1>(x); x = dpp_maxf<0x4E>(x);
  x = dpp_maxf<0x141>(x); x = dpp_maxf<0x140>(x);
  return x;
}
// full 64-lane sum: DPP within 16, DS shfl only across rows (2 ops not 6)
__device__ __forceinline__ float red64_add(float x) {
  x = red16_add(x);
  x += __shfl_xor(x, 16); x += __shfl_xor(x, 32);
  return x;
}
__device__ __forceinline__ unsigned red16_pkadd(unsigned x) {
  x = pkadd(x, (unsigned)dpp_i<0xB1>((int)x));
  x = pkadd(x, (unsigned)dpp_i<0x4E>((int)x));
  x = pkadd(x, (unsigned)dpp_i<0x141>((int)x));
  x = pkadd(x, (unsigned)dpp_i<0x140>((int)x));
  return x;
}

// attr fragments: lane slice g, j = ks*32 + g*8 + 2p (+1); j>100 -> 0
__device__ __forceinline__ void build_bfu(float rel_b, float mg_b, int g,
                                          const float2* wtbt_s, unsigned bfu[4][4]) {
#pragma unroll
  for (int ks = 0; ks < 4; ++ks) {
#pragma unroll
    for (int p = 0; p < 4; ++p) {
      int j0 = ks * 32 + g * 8 + 2 * p;
      float a0 = 0.f, a1 = 0.f;
      if (ks < 3) {
        float2 w0 = wtbt_s[j0], w1 = wtbt_s[j0 + 1];
        a0 = ref_cosf(__fmaf_rn(rel_b, w0.x, w0.y));
        a1 = ref_cosf(__fmaf_rn(rel_b, w1.x, w1.y));
      } else {
        if (j0 < 100) {
          float2 w0 = wtbt_s[j0];
          a0 = ref_cosf(__fmaf_rn(rel_b, w0.x, w0.y));
        } else if (j0 == 100) a0 = mg_b;
        if (j0 + 1 < 100) {
          float2 w1 = wtbt_s[j0 + 1];
          a1 = ref_cosf(__fmaf_rn(rel_b, w1.x, w1.y));
        } else if (j0 + 1 == 100) a1 = mg_b;
      }
      bfu[ks][p] = pk16(a0, a1);
    }
  }
}

// ---------------- k_init: W fragments + degree count (fused) ---------------
__global__ void k_init(const float* __restrict__ We,
                       const float* __restrict__ Wq, const float* __restrict__ Wk,
                       const float* __restrict__ Wv, const float* __restrict__ Wskip,
                       uint4* __restrict__ wef, uint4* __restrict__ wpf,
                       const int* __restrict__ ei, int* __restrict__ deg) {
  int idx = blockIdx.x * 256 + threadIdx.x;
  if (idx < 2048) {
    int lane = idx & 63, fi = idx >> 6;
    int ks = fi >> 3, mt = fi & 7;
    int ch = mt * 16 + (lane & 15);
    int k0 = ks * 32 + ((lane >> 4) << 3);
    U16 cv;
#pragma unroll
    for (int jj = 0; jj < 8; ++jj) {
      int j = k0 + jj;
      cv.h[jj] = (j <= 100) ? (_Float16)We[j * 128 + ch] : (_Float16)0.f;
    }
    wef[idx] = cv.u;
  } else if (idx < 2048 + 8192) {
    int i2 = idx - 2048;
    int lane = i2 & 63, fi = i2 >> 6;     // fi = (cy*4+ks)*8+nt
    int nt = fi & 7, ks = (fi >> 3) & 3, cy = fi >> 5;
    const float* W = (cy == 0) ? Wq : (cy == 1) ? Wk : (cy == 2) ? Wv : Wskip;
    int n = nt * 16 + (lane & 15);
    int k0 = ks * 32 + ((lane >> 4) << 3);
    U16 cv;
#pragma unroll
    for (int jj = 0; jj < 8; ++jj)
      cv.h[jj] = (_Float16)W[(k0 + jj) * 128 + n];
    wpf[i2] = cv.u;
  }
  if (idx < NE) atomicAdd(&deg[ei[NE + idx]], 1);
}

// ---------------- MFMA projection v2: all 4 outputs, x staged once ----------
// 512 threads; wave w: cy = w>>1, 64-col half = w&1; 32 rows per block.
// Q,K,V stored PERMUTED: channel c -> ((c>>2)&3)*32 + (c>>4)*4 + (c&3).
__global__ __launch_bounds__(512) void k_proj2(
    const float* __restrict__ x,
    const float* __restrict__ bq, const float* __restrict__ bk,
    const float* __restrict__ bv, const float* __restrict__ bskip,
    const uint4* __restrict__ wpf,
    _Float16* __restrict__ Q16, _Float16* __restrict__ K16,
    _Float16* __restrict__ V16, _Float16* __restrict__ S16)
{
  __shared__ unsigned xs[32][68];     // x rows as f16 pairs (272B pitch)
  __shared__ _Float16 os[32][136];    // output bounce (272B pitch)

  const int n0 = blockIdx.x * 32;
  const int tid = threadIdx.x;

  {
    int r = tid >> 4, c8 = (tid & 15) * 8;     // 32 rows x 16 col-groups of 8
    int row = n0 + r;
    float4 v0 = {0,0,0,0}, v1 = {0,0,0,0};
    if (row < NN) {
      const float4* xp = (const float4*)&x[(size_t)row * 128 + c8];
      v0 = xp[0]; v1 = xp[1];
    }
    unsigned* xr = &xs[r][c8 >> 1];
    xr[0] = pk16(v0.x, v0.y); xr[1] = pk16(v0.z, v0.w);
    xr[2] = pk16(v1.x, v1.y); xr[3] = pk16(v1.z, v1.w);
  }
  __syncthreads();

  const int w = tid >> 6, lane = tid & 63;
  const int cy = w >> 1, half = w & 1;

  f32x4 acc[2][4] = {};
#pragma unroll
  for (int ks = 0; ks < 4; ++ks) {
    U16 a0_, a1_;
    a0_.u = *(const uint4*)&xs[lane & 15][ks * 16 + ((lane >> 4) << 2)];
    a1_.u = *(const uint4*)&xs[16 + (lane & 15)][ks * 16 + ((lane >> 4) << 2)];
#pragma unroll
    for (int nt = 0; nt < 4; ++nt) {
      U16 b_; b_.u = wpf[((cy * 4 + ks) * 8 + half * 4 + nt) * 64 + lane];
      acc[0][nt] = __builtin_amdgcn_mfma_f32_16x16x32_f16(a0_.h, b_.h, acc[0][nt], 0, 0, 0);
      acc[1][nt] = __builtin_amdgcn_mfma_f32_16x16x32_f16(a1_.h, b_.h, acc[1][nt], 0, 0, 0);
    }
  }

  const float* biases[4] = {bq, bk, bv, bskip};
  _Float16* dsts[4] = {Q16, K16, V16, S16};
#pragma unroll
  for (int c = 0; c < 4; ++c) {
    __syncthreads();
    if (cy == c) {
#pragma unroll
      for (int nt = 0; nt < 4; ++nt) {
        int col = half * 64 + nt * 16 + (lane & 15);
        float bb = biases[c][col];
        int rb = (lane >> 4) << 2;
#pragma unroll
        for (int mt2 = 0; mt2 < 2; ++mt2)
#pragma unroll
          for (int reg = 0; reg < 4; ++reg)
            os[mt2 * 16 + rb + reg][col] = (_Float16)(acc[mt2][nt][reg] + bb);
      }
    }
    __syncthreads();
    {
      int r = tid >> 4, c8 = (tid & 15) * 8;
      int row = n0 + r;
      if (row < NN) {
        _Float16* dst = dsts[c];
        const _Float16* op = &os[r][c8];
        if (c < 3) {
#pragma unroll
          for (int q = 0; q < 2; ++q) {
            int j4 = (c8 >> 2) + q;
            int po = ((j4 & 3) << 5) | ((j4 >> 2) << 2);
            *(half4v*)&dst[(size_t)row * 128 + po] = *(const half4v*)&op[q * 4];
          }
        } else {
          *(uint4*)&dst[(size_t)row * 128 + c8] = *((const uint4*)op);
        }
      }
    }
  }
}

// ---------------- parallel CSR scan (2 kernels) ----------------------------
__global__ __launch_bounds__(256) void k_scan1(const int* __restrict__ deg,
                                               int* __restrict__ off,
                                               int* __restrict__ choff,
                                               int* __restrict__ bsum,
                                               int* __restrict__ bsumc) {
  __shared__ int s[256], sc[256];
  const int b = blockIdx.x, t = threadIdx.x;
  const int n = b * 256 + t;
  int d = (n < NN) ? deg[n] : 0;
  int c = (d + 15) >> 4;
  s[t] = d; sc[t] = c;
  __syncthreads();
  for (int o = 1; o < 256; o <<= 1) {
    int v1 = 0, v2 = 0;
    if (t >= o) { v1 = s[t - o]; v2 = sc[t - o]; }
    __syncthreads();
    if (t >= o) { s[t] += v1; sc[t] += v2; }
    __syncthreads();
  }
  if (n < NN) { off[n] = s[t] - d; choff[n] = sc[t] - c; }
  if (t == 255) { bsum[b] = s[255]; bsumc[b] = sc[255]; }
}

// merged scan2+scan3: every block redundantly scans the 196 block sums,
// then adds its exclusive base to its 256 nodes.
__global__ __launch_bounds__(256) void k_scanf(const int* __restrict__ bsum,
                                               const int* __restrict__ bsumc,
                                               int* __restrict__ off,
                                               int* __restrict__ choff) {
  __shared__ int s[256], sc[256];
  const int b = blockIdx.x, t = threadIdx.x;
  s[t] = (t < NBLK) ? bsum[t] : 0;
  sc[t] = (t < NBLK) ? bsumc[t] : 0;
  __syncthreads();
  for (int o = 1; o < 256; o <<= 1) {
    int v1 = 0, v2 = 0;
    if (t >= o) { v1 = s[t - o]; v2 = sc[t - o]; }
    __syncthreads();
    if (t >= o) { s[t] += v1; sc[t] += v2; }
    __syncthreads();
  }
  int base = (b > 0) ? s[b - 1] : 0;
  int basec = (b > 0) ? sc[b - 1] : 0;
  int n = b * 256 + t;
  if (n < NN) { off[n] += base; choff[n] += basec; }
  if (b == 0 && t == 0) { off[NN] = s[NBLK - 1]; choff[NN] = sc[NBLK - 1]; }
}

// fused: blocks [0,3125) fill elist; blocks [3125,3321) build chunk table.
// bit31 of chunk.y flags a SINGLE-chunk node (k_edge finishes it inline).
__global__ void k_fillch(const int* __restrict__ ei, const int* __restrict__ deg,
                         const int* __restrict__ off, const int* __restrict__ choff,
                         int* __restrict__ cur, int* __restrict__ elist,
                         uint2* __restrict__ chunks) {
  int b = blockIdx.x;
  if (b < 3125) {
    int e = b * 256 + threadIdx.x;
    if (e < NE) {
      int d = ei[NE + e];
      int p = atomicAdd(&cur[d], 1);
      elist[off[d] + p] = e;
    }
  } else {
    int n = (b - 3125) * 256 + threadIdx.x;
    if (n < NN) {
      int d = deg[n], o = off[n], c = choff[n];
      int nch = (d + 15) >> 4;
      unsigned flag = (nch == 1) ? 0x80000000u : 0u;
      for (int j = 0; j < nch; ++j) {
        int cnt = d - 16 * j; if (cnt > 16) cnt = 16;
        chunks[c + j] = make_uint2((unsigned)(o + 16 * j),
                                   flag | ((unsigned)n << 5) | (unsigned)cnt);
      }
    }
  }
}

// ---------------- k_edge: persistent blocks, one wave per 16-edge chunk -----
// wef staged once per block; grid-stride over chunks. Single-chunk nodes are
// finished INLINE (skip+relu+layernorm; identical math to k_comb with sc=1).
__global__ __launch_bounds__(512) void k_edge(
    const _Float16* __restrict__ Q16, const _Float16* __restrict__ K16,
    const _Float16* __restrict__ V16, const _Float16* __restrict__ S16,
    const float* __restrict__ Wt, const float* __restrict__ bt,
    const uint4* __restrict__ wefrag,
    const float* __restrict__ gamma, const float* __restrict__ beta,
    const float* __restrict__ msg, const int* __restrict__ last_update,
    const int* __restrict__ ei, const int* __restrict__ tt,
    const int* __restrict__ elist, const uint2* __restrict__ chunks,
    const int* __restrict__ choff,
    unsigned* __restrict__ numbuf, float4* __restrict__ mdm,
    float4* __restrict__ mdd, float* __restrict__ out)
{
  __shared__ uint4 wef_s[2048];
  __shared__ float2 wtbt_s[104];
  __shared__ unsigned accs_u[8][64];

  for (int i = threadIdx.x; i < 2048; i += 512) wef_s[i] = wefrag[i];
  if (threadIdx.x < 104) {
    int j = threadIdx.x;
    wtbt_s[j] = make_float2(j < TDIM ? Wt[j] : 0.f, j < TDIM ? bt[j] : 0.f);
  }
  __syncthreads();

  const int nchunks = choff[NN];
  const int wid = threadIdx.x >> 6, lane = threadIdx.x & 63;
  const int g = lane >> 4, ed = lane & 15;

  for (int c0 = blockIdx.x * 8; c0 < nchunks; c0 += EGRID * 8) {
    const int chunk = c0 + wid;
    if (chunk >= nchunks) continue;   // no block-wide sync in body: safe

    uint2 ce = chunks[chunk];
    const int estart = (int)ce.x;
    const int node = (int)((ce.y >> 5) & 0xFFFFu);
    const int cnt = (int)(ce.y & 31u);

    const int edc = (ed < cnt) ? ed : (cnt - 1);
    const int eid = elist[estart + edc];
    const int src_b = ei[eid];
    const float mg_b = msg[eid];
    const float rel_b = (float)(last_update[src_b] - tt[eid]);
    const bool valid = (ed < cnt);

    unsigned bfu[4][4];
    build_bfu(rel_b, mg_b, g, wtbt_s, bfu);

    // e via MFMA: ec[mt][r] = e[ed][mt*16+g*4+r]
    f32x4 ec[8];
#pragma unroll
    for (int mt = 0; mt < 8; ++mt) {
      f32x4 c4 = {0.f, 0.f, 0.f, 0.f};
#pragma unroll
      for (int ks = 0; ks < 4; ++ks) {
        U16 av2; av2.u = wef_s[(ks * 8 + mt) * 64 + lane];
        U16 bv2; bv2.u.x = bfu[ks][0]; bv2.u.y = bfu[ks][1];
        bv2.u.z = bfu[ks][2]; bv2.u.w = bfu[ks][3];
        c4 = __builtin_amdgcn_mfma_f32_16x16x32_f16(av2.h, bv2.h, c4, 0, 0, 0);
      }
      ec[mt] = c4;
    }

    // pack e to f16 pairs; pair layout matches permuted q/k/v uint4 blocks
    unsigned ep2[16];
#pragma unroll
    for (int mt = 0; mt < 8; ++mt) {
      ep2[mt * 2 + 0] = pk16(ec[mt][0], ec[mt][1]);
      ep2[mt * 2 + 1] = pk16(ec[mt][2], ec[mt][3]);
    }

    // per-head alpha = q.k + q.e via fdot2
    float pal[4];
    {
      const uint4* qp = (const uint4*)&Q16[(size_t)node * 128 + g * 32];
      const uint4* kp = (const uint4*)&K16[(size_t)src_b * 128 + g * 32];
#pragma unroll
      for (int i = 0; i < 4; ++i) {
        uint4 qa = qp[i], ka = kp[i];
        float p = 0.f;
        p = fdot2f(qa.x, ka.x, p); p = fdot2f(qa.y, ka.y, p);
        p = fdot2f(qa.z, ka.z, p); p = fdot2f(qa.w, ka.w, p);
        p = fdot2f(qa.x, ep2[4 * i + 0], p); p = fdot2f(qa.y, ep2[4 * i + 1], p);
        p = fdot2f(qa.z, ep2[4 * i + 2], p); p = fdot2f(qa.w, ep2[4 * i + 3], p);
        pal[i] = p;
      }
    }

    // per-head: complete dot across g-lanes (shfl), chunk softmax via DPP
    float m_[4], w_[4], d_[4];
#pragma unroll
    for (int h = 0; h < 4; ++h) {
      float p = pal[h];
      p += __shfl_xor(p, 16); p += __shfl_xor(p, 32);
      float al = valid ? p * 0.17677669529663689f : -INFINITY;
      float mm = red16_max(al);
      m_[h] = mm;
      w_[h] = __expf(al - mm);       // invalid -> 0
      d_[h] = red16_add(w_[h]);
    }

    // partial num in packed f16: w*(v+e), reduced over ed with packed DPP
    unsigned np2[16];
    {
      const uint4* vp = (const uint4*)&V16[(size_t)src_b * 128 + g * 32];
#pragma unroll
      for (int i = 0; i < 4; ++i) {
        uint4 va = vp[i];
        unsigned w2 = pk16(w_[i], w_[i]);
        np2[4 * i + 0] = pkmul(pkadd(va.x, ep2[4 * i + 0]), w2);
        np2[4 * i + 1] = pkmul(pkadd(va.y, ep2[4 * i + 1]), w2);
        np2[4 * i + 2] = pkmul(pkadd(va.z, ep2[4 * i + 2]), w2);
        np2[4 * i + 3] = pkmul(pkadd(va.w, ep2[4 * i + 3]), w2);
      }
    }
#pragma unroll
    for (int j = 0; j < 16; ++j) np2[j] = red16_pkadd(np2[j]);

    // stash reduced pairs: natural pair index P = 16i + 8(j>>1) + 2g + (j&1)
    if (ed == 0) {
#pragma unroll
      for (int i = 0; i < 4; ++i)
#pragma unroll
        for (int j = 0; j < 4; ++j)
          accs_u[wid][16 * i + 8 * (j >> 1) + 2 * g + (j & 1)] = np2[4 * i + j];
    }
    __asm__ volatile("s_waitcnt lgkmcnt(0)" ::: "memory");

    unsigned pr = accs_u[wid][lane];
    if (!(ce.y & 0x80000000u)) {
      numbuf[(size_t)chunk * 64 + lane] = pr;
      if (lane == 0) {
        mdm[chunk] = make_float4(m_[0], m_[1], m_[2], m_[3]);
        mdd[chunk] = make_float4(d_[0], d_[1], d_[2], d_[3]);
      }
    } else {
      // single-chunk node: finish inline (sc = exp(m-M) = 1)
      float dg = (g & 2) ? ((g & 1) ? d_[3] : d_[2])
                         : ((g & 1) ? d_[1] : d_[0]);
      float iv = 1.f / (dg + 1e-16f);
      U4h u; u.u = pr;
      U4h s2; s2.u = *(const unsigned*)&S16[(size_t)node * 128 + 2 * lane];
      float r0 = fmaxf(fmaf((float)u.h.x, iv, (float)s2.h.x), 0.f);
      float r1 = fmaxf(fmaf((float)u.h.y, iv, (float)s2.h.y), 0.f);
      float sum = red64_add(r0 + r1);
      float mu = sum * 0.0078125f;
      float dd0 = r0 - mu, dd1 = r1 - mu;
      float vs = red64_add(dd0 * dd0 + dd1 * dd1);
      float rstd = rsqrtf(vs * 0.0078125f + 1e-5f);
      float2 gm = ((const float2*)gamma)[lane], bb = ((const float2*)beta)[lane];
      ((float2*)out)[node * 64 + lane] =
          make_float2(dd0 * rstd * gm.x + bb.x, dd1 * rstd * gm.y + bb.y);
    }
  }
}

// ---------------- k_comb: per-head flash combine (multi-chunk nodes only) ---
__global__ __launch_bounds__(256) void k_comb(
    const unsigned* __restrict__ numbuf, const float* __restrict__ mdmf,
    const float* __restrict__ mddf, const _Float16* __restrict__ S16,
    const float* __restrict__ gamma, const float* __restrict__ beta,
    const int* __restrict__ choff, float* __restrict__ out)
{
  const int wid = threadIdx.x >> 6, lane = threadIdx.x & 63;
  const int node = blockIdx.x * 4 + wid;
  const int g = lane >> 4;          // head of channels 2*lane, 2*lane+1
  const int c0 = choff[node], c1 = choff[node + 1];
  if (c1 - c0 == 1) return;         // finished inline by k_edge

  float M = -INFINITY;
  for (int c = c0; c < c1; ++c) M = fmaxf(M, mdmf[c * 4 + g]);

  float den = 0.f, n0 = 0.f, n1 = 0.f;
  for (int c = c0; c < c1; ++c) {
    float sc = __expf(mdmf[c * 4 + g] - M);
    den = fmaf(mddf[c * 4 + g], sc, den);
    U4h u; u.u = numbuf[(size_t)c * 64 + lane];
    n0 = fmaf((float)u.h.x, sc, n0);
    n1 = fmaf((float)u.h.y, sc, n1);
  }

  float iv = 1.f / (den + 1e-16f);
  U4h s2; s2.u = *(const unsigned*)&S16[(size_t)node * 128 + 2 * lane];
  float r0 = fmaxf(fmaf(n0, iv, (float)s2.h.x), 0.f);
  float r1 = fmaxf(fmaf(n1, iv, (float)s2.h.y), 0.f);

  float sum = red64_add(r0 + r1);
  float mu = sum * 0.0078125f;
  float d0 = r0 - mu, d1 = r1 - mu;
  float vs = red64_add(d0 * d0 + d1 * d1);
  float rstd = rsqrtf(vs * 0.0078125f + 1e-5f);
  float2 gm = ((const float2*)gamma)[lane], bb = ((const float2*)beta)[lane];
  ((float2*)out)[node * 64 + lane] =
      make_float2(d0 * rstd * gm.x + bb.x, d1 * rstd * gm.y + bb.y);
}

// ---------------- launch ----------------
// ws (bytes): Q16 0 | S16 12.8M | K16 25.6M | V16 38.4M | numbuf 51.2M (25.6M)
//   deg 76.8M | cur 77.0M | off 77.2M | choff 77,400,064 | elist 77,600,128
//   wef 80,800,128 | chunks 80,832,896 | mdm 81,632,896 | mdd 83,232,896
//   wpf 84,832,896 (128KB) | bsum 84,963,968 | bsumc 84,964,968 | end 84,965,968
extern "C" void kernel_launch(void* const* d_in, const int* in_sizes, int n_in,
                              void* d_out, int out_size, void* d_ws, size_t ws_size,
                              hipStream_t stream)
{
  (void)in_sizes; (void)n_in; (void)out_size;
  if (ws_size < 84965968u) return;

  const float* x     = (const float*)d_in[0];
  const float* msg   = (const float*)d_in[1];
  const float* Wt    = (const float*)d_in[2];
  const float* bt    = (const float*)d_in[3];
  const float* Wq    = (const float*)d_in[4];
  const float* bq    = (const float*)d_in[5];
  const float* Wk    = (const float*)d_in[6];
  const float* bk    = (const float*)d_in[7];
  const float* Wv    = (const float*)d_in[8];
  const float* bv    = (const float*)d_in[9];
  const float* We    = (const float*)d_in[10];
  const float* Wskip = (const float*)d_in[11];
  const float* bskip = (const float*)d_in[12];
  const float* gamma = (const float*)d_in[13];
  const float* beta  = (const float*)d_in[14];
  const int* last_update = (const int*)d_in[15];
  const int* ei    = (const int*)d_in[16];
  const int* tt    = (const int*)d_in[17];

  char* ws = (char*)d_ws;
  _Float16* Q16 = (_Float16*)(ws);
  _Float16* S16 = (_Float16*)(ws + 12800000);
  _Float16* K16 = (_Float16*)(ws + 25600000);
  _Float16* V16 = (_Float16*)(ws + 38400000);
  unsigned* numbuf = (unsigned*)(ws + 51200000);
  int* deg   = (int*)(ws + 76800000);
  int* cur   = (int*)(ws + 77000000);
  int* off   = (int*)(ws + 77200000);
  int* choff = (int*)(ws + 77400064);
  int* elist = (int*)(ws + 77600128);
  uint4* wef = (uint4*)(ws + 80800128);
  uint2* chunks = (uint2*)(ws + 80832896);
  float4* mdm = (float4*)(ws + 81632896);
  float4* mdd = (float4*)(ws + 83232896);
  uint4* wpf = (uint4*)(ws + 84832896);
  int* bsum  = (int*)(ws + 84963968);
  int* bsumc = (int*)(ws + 84964968);

  (void)hipMemsetAsync(deg, 0, 400000, stream);        // deg + cur
  k_init<<<(NE + 255) / 256, 256, 0, stream>>>(We, Wq, Wk, Wv, Wskip, wef, wpf,
                                               ei, deg);
  k_scan1<<<NBLK, 256, 0, stream>>>(deg, off, choff, bsum, bsumc);
  k_scanf<<<NBLK, 256, 0, stream>>>(bsum, bsumc, off, choff);
  k_fillch<<<3125 + (NN + 255) / 256, 256, 0, stream>>>(ei, deg, off, choff,
                                                        cur, elist, chunks);
  k_proj2<<<(NN + 31) / 32, 512, 0, stream>>>(x, bq, bk, bv, bskip, wpf,
                                              Q16, K16, V16, S16);
  k_edge<<<EGRID, 512, 0, stream>>>(Q16, K16, V16, S16, Wt, bt, wef,
                                    gamma, beta, msg, last_update, ei, tt,
                                    elist, chunks, choff, numbuf, mdm, mdd,
                                    (float*)d_out);
  k_comb<<<NN / 4, 256, 0, stream>>>(numbuf, (const float*)mdm, (const float*)mdd,
                                     S16, gamma, beta, choff, (float*)d_out);
}